// Round 1
// baseline (1176.632 us; speedup 1.0000x reference)
//
#include <hip/hip_runtime.h>

typedef unsigned short u16;
typedef __attribute__((ext_vector_type(8))) short bf16x8;
typedef __attribute__((ext_vector_type(4))) float f32x4;

__device__ __forceinline__ u16 f2bf(float f) {
  union { float f; unsigned u; } v; v.f = f;
  unsigned u = v.u;
  u += 0x7fffu + ((u >> 16) & 1u);
  return (u16)(u >> 16);
}
__device__ __forceinline__ float bf2f(u16 h) {
  union { unsigned u; float f; } v; v.u = ((unsigned)h) << 16;
  return v.f;
}

__device__ __forceinline__ void gll16(const void* g, void* l) {
  __builtin_amdgcn_global_load_lds(
      (const __attribute__((address_space(1))) void*)g,
      (__attribute__((address_space(3))) void*)l, 16, 0, 0);
}

// ---------------------------------------------------------------------------
// P1: x[b][c][n] f32 -> xt[b][n][c] bf16   (C=512, N=1600)
// ---------------------------------------------------------------------------
__global__ __launch_bounds__(256) void transp_cast_x(const float* __restrict__ x,
                                                     u16* __restrict__ xt) {
  __shared__ float t[32][33];
  int b = blockIdx.z;
  const float* xb = x + (size_t)b * 819200;
  u16* xtb = xt + (size_t)b * 819200;
  int n0 = blockIdx.x * 32, c0 = blockIdx.y * 32;
  int tx = threadIdx.x & 31, ty = threadIdx.x >> 5;  // ty in 0..7
#pragma unroll
  for (int k = 0; k < 4; k++) {
    int c = ty + k * 8;
    t[c][tx] = xb[(size_t)(c0 + c) * 1600 + n0 + tx];
  }
  __syncthreads();
#pragma unroll
  for (int k = 0; k < 4; k++) {
    int n = ty + k * 8;
    xtb[(size_t)(n0 + n) * 512 + c0 + tx] = f2bf(t[tx][n]);
  }
}

// P2: cast w_e / w_q (256x512 each) to bf16
__global__ void cast_w(const float* __restrict__ we, const float* __restrict__ wq,
                       u16* __restrict__ oe, u16* __restrict__ oq) {
  int i = blockIdx.x * 256 + threadIdx.x;  // 131072 total
  oe[i] = f2bf(we[i]);
  oq[i] = f2bf(wq[i]);
}

// P3: w[o][c][ky][kx] f32 -> wr[o][t*512+c] bf16, t=ky*3+kx  (512x512x9)
__global__ void repack_wc(const float* __restrict__ w, u16* __restrict__ wr) {
  int idx = blockIdx.x * 256 + threadIdx.x;  // 2359296 total
  int o = idx / 4608;
  int r = idx - o * 4608;
  int t = r >> 9;
  int c = r & 511;
  wr[idx] = f2bf(w[o * 4608 + c * 9 + t]);
}

// P4: zero (att buffers, contiguous region)
__global__ void zero_mem(uint4* __restrict__ p, long n) {
  long i = (long)blockIdx.x * blockDim.x + threadIdx.x;
  long stride = (long)gridDim.x * blockDim.x;
  uint4 z; z.x = 0; z.y = 0; z.z = 0; z.w = 0;
  for (; i < n; i += stride) p[i] = z;
}

// ---------------------------------------------------------------------------
// Generic A*B^T bf16 GEMM, 128x128 tile, BK=32, batched over blockIdx.z.
// C[i][j] = sum_k A[i][k]*B[j][k].  lda=ldb=K.
// MODE 0: store bf16, ldc=N. MODE 1: store bf16 of exp(). MODE 2: store bf16
// to padded pixel layout [ (i/40+1)*42 + i%40+1 ][ j ], ldc=512.
// ---------------------------------------------------------------------------
template <int MODE>
__global__ __launch_bounds__(256) void gemm_abt(const u16* __restrict__ A,
                                                const u16* __restrict__ B,
                                                u16* __restrict__ C, int M, int N,
                                                int K, long sA, long sB, long sC) {
  __shared__ u16 lds_a[128 * 32];
  __shared__ u16 lds_b[128 * 32];
  int tid = threadIdx.x;
  int bz = blockIdx.z;
  const u16* Ab = A + (size_t)bz * sA;
  const u16* Bb = B + (size_t)bz * sB;
  u16* Cb = C + (size_t)bz * sC;
  int m0 = blockIdx.x * 128, n0 = blockIdx.y * 128;

  int ra0 = m0 + (tid >> 2);           ra0 = ra0 < M ? ra0 : M - 1;
  int ra1 = m0 + ((tid + 256) >> 2);   ra1 = ra1 < M ? ra1 : M - 1;
  int rb0 = n0 + (tid >> 2);           rb0 = rb0 < N ? rb0 : N - 1;
  int rb1 = n0 + ((tid + 256) >> 2);   rb1 = rb1 < N ? rb1 : N - 1;
  int chb = (tid & 3) * 16;
  const char* a0 = (const char*)(Ab + (size_t)ra0 * K) + chb;
  const char* a1 = (const char*)(Ab + (size_t)ra1 * K) + chb;
  const char* b0 = (const char*)(Bb + (size_t)rb0 * K) + chb;
  const char* b1 = (const char*)(Bb + (size_t)rb1 * K) + chb;
  u16* la0 = &lds_a[tid * 8];
  u16* la1 = &lds_a[(tid + 256) * 8];
  u16* lb0 = &lds_b[tid * 8];
  u16* lb1 = &lds_b[(tid + 256) * 8];

  const f32x4 fzero = {0.f, 0.f, 0.f, 0.f};
  f32x4 acc[4][4];
#pragma unroll
  for (int mi = 0; mi < 4; mi++)
#pragma unroll
    for (int ni = 0; ni < 4; ni++) acc[mi][ni] = fzero;

  int wid = tid >> 6, lane = tid & 63;
  int wm = wid & 1, wn = wid >> 1;
  int lrow = lane & 15, lquad = lane >> 4;

  int ksteps = K >> 5;
  for (int ks = 0; ks < ksteps; ks++) {
    gll16(a0, la0);
    gll16(a1, la1);
    gll16(b0, lb0);
    gll16(b1, lb1);
    a0 += 64; a1 += 64; b0 += 64; b1 += 64;
    __syncthreads();
    bf16x8 bv[4];
#pragma unroll
    for (int ni = 0; ni < 4; ni++)
      bv[ni] = *(const bf16x8*)&lds_b[(wn * 64 + ni * 16 + lrow) * 32 + lquad * 8];
#pragma unroll
    for (int mi = 0; mi < 4; mi++) {
      bf16x8 av = *(const bf16x8*)&lds_a[(wm * 64 + mi * 16 + lrow) * 32 + lquad * 8];
#pragma unroll
      for (int ni = 0; ni < 4; ni++)
        acc[mi][ni] =
            __builtin_amdgcn_mfma_f32_16x16x32_bf16(av, bv[ni], acc[mi][ni], 0, 0, 0);
    }
    __syncthreads();
  }

#pragma unroll
  for (int mi = 0; mi < 4; mi++) {
#pragma unroll
    for (int r = 0; r < 4; r++) {
      int i = m0 + wm * 64 + mi * 16 + lquad * 4 + r;
      if (i >= M) continue;
#pragma unroll
      for (int ni = 0; ni < 4; ni++) {
        int j = n0 + wn * 64 + ni * 16 + lrow;
        if (j >= N) continue;
        float v = acc[mi][ni][r];
        if (MODE == 1) v = __expf(v);
        if (MODE == 2) {
          int y = i / 40, x = i - y * 40;
          Cb[(size_t)((y + 1) * 42 + (x + 1)) * 512 + j] = f2bf(v);
        } else {
          Cb[(size_t)i * N + j] = f2bf(v);
        }
      }
    }
  }
}

// ---------------------------------------------------------------------------
// K3a: transpose E[b][1600][1600] -> ET (bf16)
// ---------------------------------------------------------------------------
__global__ __launch_bounds__(256) void transp_bf(const u16* __restrict__ E,
                                                 u16* __restrict__ ET) {
  __shared__ u16 t[64][65];
  int b = blockIdx.z;
  const u16* Eb = E + (size_t)b * 2560000;
  u16* Tb = ET + (size_t)b * 2560000;
  int i0 = blockIdx.x * 64, j0 = blockIdx.y * 64;
  int tx = threadIdx.x & 63, ty = threadIdx.x >> 6;  // ty 0..3
#pragma unroll
  for (int k = 0; k < 16; k++) {
    int r = ty + k * 4;
    t[r][tx] = Eb[(size_t)(i0 + r) * 1600 + j0 + tx];
  }
  __syncthreads();
#pragma unroll
  for (int k = 0; k < 16; k++) {
    int r = ty + k * 4;
    Tb[(size_t)(j0 + r) * 1600 + i0 + tx] = t[tx][r];
  }
}

// K3b: row sums of src[b][row][0..1600) -> dst[b*1600+row] = 1/sum
__global__ __launch_bounds__(256) void rowsum_recip(const u16* __restrict__ src,
                                                    float* __restrict__ dst) {
  int row = blockIdx.x;
  int b = blockIdx.y;
  const u16* p = src + (size_t)b * 2560000 + (size_t)row * 1600;
  float s = 0.f;
  for (int i = threadIdx.x; i < 1600; i += 256) s += bf2f(p[i]);
  __shared__ float red[256];
  red[threadIdx.x] = s;
  __syncthreads();
  for (int st = 128; st > 0; st >>= 1) {
    if (threadIdx.x < st) red[threadIdx.x] += red[threadIdx.x + st];
    __syncthreads();
  }
  if (threadIdx.x == 0) dst[b * 1600 + row] = 1.0f / red[0];
}

// K3c: out[b][c][i] = bf16( x[b][c][i] * rZ[b][i] )
__global__ void scale_cast(const float* __restrict__ x, const float* __restrict__ rZ,
                           u16* __restrict__ out) {
  size_t idx = (size_t)blockIdx.x * 256 + threadIdx.x;  // 13107200 total
  int b = (int)(idx / 819200);
  int i = (int)(idx % 1600);
  out[idx] = f2bf(x[idx] * rZ[b * 1600 + i]);
}

// ---------------------------------------------------------------------------
// K5: conv3x3 as A*B^T GEMM. W: [512][4608] (k = t*512+c), ATT: padded
// pixel-major [b][42*42][512] bf16.  out[b][cho+o][p] f32.
// ---------------------------------------------------------------------------
__global__ __launch_bounds__(256) void conv_gemm(const u16* __restrict__ W,
                                                 const u16* __restrict__ ATT,
                                                 float* __restrict__ out, int cho) {
  __shared__ u16 lds_a[128 * 32];
  __shared__ u16 lds_b[128 * 32];
  int tid = threadIdx.x;
  int b = blockIdx.z;
  const u16* attb = ATT + (size_t)b * 903168;
  float* outb = out + (size_t)b * 1638400;
  int p0 = blockIdx.x * 128, o0 = blockIdx.y * 128;

  int chb = (tid & 3) * 16;
  const char* a0 = (const char*)(W + (size_t)(o0 + (tid >> 2)) * 4608) + chb;
  const char* a1 = (const char*)(W + (size_t)(o0 + ((tid + 256) >> 2)) * 4608) + chb;
  int pr0 = p0 + (tid >> 2);           pr0 = pr0 < 1600 ? pr0 : 1599;
  int pr1 = p0 + ((tid + 256) >> 2);   pr1 = pr1 < 1600 ? pr1 : 1599;
  int y0 = pr0 / 40, x0 = pr0 - y0 * 40;
  int y1 = pr1 / 40, x1 = pr1 - y1 * 40;
  const char* b0 = (const char*)(attb + (size_t)(y0 * 42 + x0) * 512) + chb;
  const char* b1 = (const char*)(attb + (size_t)(y1 * 42 + x1) * 512) + chb;
  u16* la0 = &lds_a[tid * 8];
  u16* la1 = &lds_a[(tid + 256) * 8];
  u16* lb0 = &lds_b[tid * 8];
  u16* lb1 = &lds_b[(tid + 256) * 8];

  const f32x4 fzero = {0.f, 0.f, 0.f, 0.f};
  f32x4 acc[4][4];
#pragma unroll
  for (int mi = 0; mi < 4; mi++)
#pragma unroll
    for (int ni = 0; ni < 4; ni++) acc[mi][ni] = fzero;

  int wid = tid >> 6, lane = tid & 63;
  int wm = wid & 1, wn = wid >> 1;
  int lrow = lane & 15, lquad = lane >> 4;

  for (int ks = 0; ks < 144; ks++) {
    int t = ks >> 4, kc = ks & 15;
    int dy = t / 3, dx = t - dy * 3;
    long boff = (long)(dy * 42 + dx) * 1024 + (long)kc * 64;
    gll16(a0 + (long)ks * 64, la0);
    gll16(a1 + (long)ks * 64, la1);
    gll16(b0 + boff, lb0);
    gll16(b1 + boff, lb1);
    __syncthreads();
    bf16x8 bv[4];
#pragma unroll
    for (int ni = 0; ni < 4; ni++)
      bv[ni] = *(const bf16x8*)&lds_b[(wn * 64 + ni * 16 + lrow) * 32 + lquad * 8];
#pragma unroll
    for (int mi = 0; mi < 4; mi++) {
      bf16x8 av = *(const bf16x8*)&lds_a[(wm * 64 + mi * 16 + lrow) * 32 + lquad * 8];
#pragma unroll
      for (int ni = 0; ni < 4; ni++)
        acc[mi][ni] =
            __builtin_amdgcn_mfma_f32_16x16x32_bf16(av, bv[ni], acc[mi][ni], 0, 0, 0);
    }
    __syncthreads();
  }

#pragma unroll
  for (int mi = 0; mi < 4; mi++) {
#pragma unroll
    for (int r = 0; r < 4; r++) {
      int o = o0 + wm * 64 + mi * 16 + lquad * 4 + r;
#pragma unroll
      for (int ni = 0; ni < 4; ni++) {
        int p = p0 + wn * 64 + ni * 16 + lrow;
        if (p < 1600) outb[(size_t)(cho + o) * 1600 + p] = acc[mi][ni][r];
      }
    }
  }
}

// ---------------------------------------------------------------------------
extern "C" void kernel_launch(void* const* d_in, const int* in_sizes, int n_in,
                              void* d_out, int out_size, void* d_ws, size_t ws_size,
                              hipStream_t stream) {
  const float* ex = (const float*)d_in[0];
  const float* qu = (const float*)d_in[1];
  const float* w_e = (const float*)d_in[2];
  const float* w_q = (const float*)d_in[3];
  const float* w_c1 = (const float*)d_in[4];
  const float* w_c2 = (const float*)d_in[5];
  float* out = (float*)d_out;
  char* ws = (char*)d_ws;

  u16* E     = (u16*)(ws + 0L);           // 81,920,000
  u16* ET    = (u16*)(ws + 81920000L);    // 81,920,000
  u16* xt_e  = (u16*)(ws + 163840000L);   // 26,214,400  (reused as ebf)
  u16* xt_q  = (u16*)(ws + 190054400L);   // 26,214,400  (reused as qbf)
  u16* ecorr = (u16*)(ws + 216268800L);   // 13,107,200
  u16* qcorr = (u16*)(ws + 229376000L);   // 13,107,200
  u16* att_e = (u16*)(ws + 242483200L);   // 28,901,376
  u16* att_q = (u16*)(ws + 271384576L);   // 28,901,376
  u16* w_ebf = (u16*)(ws + 300285952L);   // 262,144
  u16* w_qbf = (u16*)(ws + 300548096L);   // 262,144
  u16* wr1   = (u16*)(ws + 300810240L);   // 4,718,592
  u16* wr2   = (u16*)(ws + 305528832L);   // 4,718,592
  float* rZ1 = (float*)(ws + 310247424L); // 102,400
  float* rZ2 = (float*)(ws + 310349824L); // 102,400  (total ~296 MiB)

  // prep
  transp_cast_x<<<dim3(50, 16, 16), 256, 0, stream>>>(ex, xt_e);
  transp_cast_x<<<dim3(50, 16, 16), 256, 0, stream>>>(qu, xt_q);
  cast_w<<<dim3(512), 256, 0, stream>>>(w_e, w_q, w_ebf, w_qbf);
  repack_wc<<<dim3(9216), 256, 0, stream>>>(w_c1, wr1);
  repack_wc<<<dim3(9216), 256, 0, stream>>>(w_c2, wr2);
  zero_mem<<<dim3(2048), 256, 0, stream>>>((uint4*)att_e, 3612672L);

  // K1: corr_t[b][n][o] = sum_c xt[n,c] * w[o,c]
  gemm_abt<0><<<dim3(13, 2, 16), 256, 0, stream>>>(xt_e, w_ebf, ecorr, 1600, 256, 512,
                                                   819200L, 0L, 409600L);
  gemm_abt<0><<<dim3(13, 2, 16), 256, 0, stream>>>(xt_q, w_qbf, qcorr, 1600, 256, 512,
                                                   819200L, 0L, 409600L);
  // K2: E[b][n][m] = exp( sum_o ecorr[n,o]*qcorr[m,o] )
  gemm_abt<1><<<dim3(13, 13, 16), 256, 0, stream>>>(ecorr, qcorr, E, 1600, 1600, 256,
                                                    409600L, 409600L, 2560000L);
  // K3
  transp_bf<<<dim3(25, 25, 16), 256, 0, stream>>>(E, ET);
  rowsum_recip<<<dim3(1600, 16), 256, 0, stream>>>(E, rZ2);   // Z2 = row sums of E
  rowsum_recip<<<dim3(1600, 16), 256, 0, stream>>>(ET, rZ1);  // Z1 = col sums of E
  u16* ebf = xt_e;  // xt dead after K1
  u16* qbf = xt_q;
  scale_cast<<<dim3(51200), 256, 0, stream>>>(ex, rZ1, ebf);
  scale_cast<<<dim3(51200), 256, 0, stream>>>(qu, rZ2, qbf);

  // K4: att_q_t[p][c] = sum_i E[p,i]*ebf[c,i] ; att_e_t[p][c] = sum_i ET[p,i]*qbf[c,i]
  gemm_abt<2><<<dim3(13, 4, 16), 256, 0, stream>>>(E, ebf, att_q, 1600, 512, 1600,
                                                   2560000L, 819200L, 903168L);
  gemm_abt<2><<<dim3(13, 4, 16), 256, 0, stream>>>(ET, qbf, att_e, 1600, 512, 1600,
                                                   2560000L, 819200L, 903168L);

  // K5: convs. conv(exemplar_att, w_c1) -> ch 0..511 ; conv(query_att, w_c2) -> 512..1023
  conv_gemm<<<dim3(13, 4, 16), 256, 0, stream>>>(wr1, att_e, out, 0);
  conv_gemm<<<dim3(13, 4, 16), 256, 0, stream>>>(wr2, att_q, out, 512);
}

// Round 2
// 918.777 us; speedup vs baseline: 1.2807x; 1.2807x over previous
//
#include <hip/hip_runtime.h>

typedef unsigned short u16;
typedef __attribute__((ext_vector_type(8))) short bf16x8;
typedef __attribute__((ext_vector_type(4))) float f32x4;

__device__ __forceinline__ u16 f2bf(float f) {
  union { float f; unsigned u; } v; v.f = f;
  unsigned u = v.u;
  u += 0x7fffu + ((u >> 16) & 1u);
  return (u16)(u >> 16);
}

__device__ __forceinline__ void gll16(const void* g, void* l) {
  __builtin_amdgcn_global_load_lds(
      (const __attribute__((address_space(1))) void*)g,
      (__attribute__((address_space(3))) void*)l, 16, 0, 0);
}

// ---------------------------------------------------------------------------
// P1: x[b][c][n] f32 -> xt[b][n][c] bf16   (C=512, N=1600), both inputs
// ---------------------------------------------------------------------------
__global__ __launch_bounds__(256) void transp_cast_x2(const float* __restrict__ ex,
                                                      const float* __restrict__ qu,
                                                      u16* __restrict__ xte,
                                                      u16* __restrict__ xtq) {
  __shared__ float t[32][33];
  int z = blockIdx.z;
  int b = z & 15;
  const float* xb = (z < 16 ? ex : qu) + (size_t)b * 819200;
  u16* xtb = (z < 16 ? xte : xtq) + (size_t)b * 819200;
  int n0 = blockIdx.x * 32, c0 = blockIdx.y * 32;
  int tx = threadIdx.x & 31, ty = threadIdx.x >> 5;
#pragma unroll
  for (int k = 0; k < 4; k++) {
    int c = ty + k * 8;
    t[c][tx] = xb[(size_t)(c0 + c) * 1600 + n0 + tx];
  }
  __syncthreads();
#pragma unroll
  for (int k = 0; k < 4; k++) {
    int n = ty + k * 8;
    xtb[(size_t)(n0 + n) * 512 + c0 + tx] = f2bf(t[tx][n]);
  }
}

// P2: cast w_e / w_q (256x512 each) to bf16
__global__ void cast_w(const float* __restrict__ we, const float* __restrict__ wq,
                       u16* __restrict__ oe, u16* __restrict__ oq) {
  int i = blockIdx.x * 256 + threadIdx.x;
  oe[i] = f2bf(we[i]);
  oq[i] = f2bf(wq[i]);
}

// P3: w[o][c][ky][kx] f32 -> wr[o][t*512+c] bf16 (both conv weights)
__global__ void repack_wc(const float* __restrict__ w1, const float* __restrict__ w2,
                          u16* __restrict__ o1, u16* __restrict__ o2) {
  const float* w = blockIdx.y ? w2 : w1;
  u16* wr = blockIdx.y ? o2 : o1;
  int idx = blockIdx.x * 256 + threadIdx.x;  // 2359296 total
  int o = idx / 4608;
  int r = idx - o * 4608;
  int t = r >> 9;
  int c = r & 511;
  wr[idx] = f2bf(w[o * 4608 + c * 9 + t]);
}

// P4: zero att buffers + Z buffers
__global__ void zero_mem(uint4* __restrict__ p, long n) {
  long i = (long)blockIdx.x * blockDim.x + threadIdx.x;
  long stride = (long)gridDim.x * blockDim.x;
  uint4 z; z.x = 0; z.y = 0; z.z = 0; z.w = 0;
  for (; i < n; i += stride) p[i] = z;
}

// ---------------------------------------------------------------------------
// Generic A*B^T bf16 GEMM, 128x128 tile, BK=64, XOR-swizzled LDS,
// dual problem sets selected by blockIdx.z (z<16 -> set1, else set2).
// MODE 0: store bf16 C[i*N+j].  MODE 2: store bf16 to padded pixel layout.
// ---------------------------------------------------------------------------
template <int MODE>
__global__ __launch_bounds__(256) void gemm_bt64(
    const u16* __restrict__ A, const u16* __restrict__ B, u16* __restrict__ C,
    const u16* __restrict__ A2, const u16* __restrict__ B2, u16* __restrict__ C2,
    int M, int N, int K, long sA, long sB, long sC) {
  __shared__ u16 lds_a[128 * 64];
  __shared__ u16 lds_b[128 * 64];
  int tid = threadIdx.x;
  int z = blockIdx.z, b = z & 15;
  const u16* Ab = (z < 16 ? A : A2) + (size_t)b * sA;
  const u16* Bb = (z < 16 ? B : B2) + (size_t)b * sB;
  u16* Cb = (z < 16 ? C : C2) + (size_t)b * sC;
  int m0 = blockIdx.x * 128, n0 = blockIdx.y * 128;

  int rsub = tid >> 3;                     // 0..31
  int gch = (tid & 7) ^ (rsub & 7);        // swizzled 16B chunk to fetch
  long Kb = (long)K * 2;
  const char* pa[4];
  const char* pb[4];
#pragma unroll
  for (int c = 0; c < 4; c++) {
    int ra = m0 + 32 * c + rsub; ra = ra < M ? ra : M - 1;
    int rb = n0 + 32 * c + rsub; rb = rb < N ? rb : N - 1;
    pa[c] = (const char*)Ab + (long)ra * Kb + gch * 16;
    pb[c] = (const char*)Bb + (long)rb * Kb + gch * 16;
  }

  const f32x4 fzero = {0.f, 0.f, 0.f, 0.f};
  f32x4 acc[4][4];
#pragma unroll
  for (int mi = 0; mi < 4; mi++)
#pragma unroll
    for (int ni = 0; ni < 4; ni++) acc[mi][ni] = fzero;

  int wid = tid >> 6, lane = tid & 63;
  int wm = wid & 1, wn = wid >> 1;
  int lrow = lane & 15, lquad = lane >> 4;
  int sl = lrow & 7;

  int ksteps = K >> 6;
  for (int ks = 0; ks < ksteps; ks++) {
#pragma unroll
    for (int c = 0; c < 4; c++) {
      gll16(pa[c], (char*)lds_a + c * 4096 + tid * 16);
      gll16(pb[c], (char*)lds_b + c * 4096 + tid * 16);
      pa[c] += 128; pb[c] += 128;
    }
    __syncthreads();
#pragma unroll
    for (int k2 = 0; k2 < 2; k2++) {
      int sel = ((k2 << 2) | lquad) ^ sl;
      bf16x8 bv[4];
#pragma unroll
      for (int ni = 0; ni < 4; ni++) {
        int rowb = wn * 64 + ni * 16 + lrow;
        bv[ni] = *(const bf16x8*)((const char*)lds_b + rowb * 128 + sel * 16);
      }
#pragma unroll
      for (int mi = 0; mi < 4; mi++) {
        int rowa = wm * 64 + mi * 16 + lrow;
        bf16x8 av = *(const bf16x8*)((const char*)lds_a + rowa * 128 + sel * 16);
#pragma unroll
        for (int ni = 0; ni < 4; ni++)
          acc[mi][ni] =
              __builtin_amdgcn_mfma_f32_16x16x32_bf16(av, bv[ni], acc[mi][ni], 0, 0, 0);
      }
    }
    __syncthreads();
  }

#pragma unroll
  for (int mi = 0; mi < 4; mi++) {
#pragma unroll
    for (int r = 0; r < 4; r++) {
      int i = m0 + wm * 64 + mi * 16 + lquad * 4 + r;
      if (i >= M) continue;
#pragma unroll
      for (int ni = 0; ni < 4; ni++) {
        int j = n0 + wn * 64 + ni * 16 + lrow;
        if (j >= N) continue;
        float v = acc[mi][ni][r];
        if (MODE == 2) {
          int y = i / 40, x = i - y * 40;
          Cb[(size_t)((y + 1) * 42 + (x + 1)) * 512 + j] = f2bf(v);
        } else {
          Cb[(size_t)i * N + j] = f2bf(v);
        }
      }
    }
  }
}

// ---------------------------------------------------------------------------
// K2: E = exp(ecorr * qcorr^T)  [1600x1600 per batch, K=256]
// Fused epilogue: E (coalesced 16B rows), ET (LDS transpose), Zrow/Zcol sums
// via shuffle + atomics.
// ---------------------------------------------------------------------------
__global__ __launch_bounds__(256) void gemm_corr_exp(
    const u16* __restrict__ A, const u16* __restrict__ B, u16* __restrict__ E,
    u16* __restrict__ ET, float* __restrict__ Zrow, float* __restrict__ Zcol) {
  __shared__ u16 lds_a[128 * 64];
  __shared__ u16 lds_b[128 * 64];
  int tid = threadIdx.x;
  int b = blockIdx.z;
  const u16* Ab = A + (size_t)b * 409600;
  const u16* Bb = B + (size_t)b * 409600;
  u16* Eb = E + (size_t)b * 2560000;
  u16* ETb = ET + (size_t)b * 2560000;
  int m0 = blockIdx.x * 128, n0 = blockIdx.y * 128;

  int rsub = tid >> 3;
  int gch = (tid & 7) ^ (rsub & 7);
  const char* pa[4];
  const char* pb[4];
#pragma unroll
  for (int c = 0; c < 4; c++) {
    int ra = m0 + 32 * c + rsub; ra = ra < 1600 ? ra : 1599;
    int rb = n0 + 32 * c + rsub; rb = rb < 1600 ? rb : 1599;
    pa[c] = (const char*)(Ab + (size_t)ra * 256) + gch * 16;
    pb[c] = (const char*)(Bb + (size_t)rb * 256) + gch * 16;
  }

  const f32x4 fzero = {0.f, 0.f, 0.f, 0.f};
  f32x4 acc[4][4];
#pragma unroll
  for (int mi = 0; mi < 4; mi++)
#pragma unroll
    for (int ni = 0; ni < 4; ni++) acc[mi][ni] = fzero;

  int wid = tid >> 6, lane = tid & 63;
  int wm = wid & 1, wn = wid >> 1;
  int lrow = lane & 15, lquad = lane >> 4;
  int sl = lrow & 7;

  for (int ks = 0; ks < 4; ks++) {
#pragma unroll
    for (int c = 0; c < 4; c++) {
      gll16(pa[c], (char*)lds_a + c * 4096 + tid * 16);
      gll16(pb[c], (char*)lds_b + c * 4096 + tid * 16);
      pa[c] += 128; pb[c] += 128;
    }
    __syncthreads();
#pragma unroll
    for (int k2 = 0; k2 < 2; k2++) {
      int sel = ((k2 << 2) | lquad) ^ sl;
      bf16x8 bv[4];
#pragma unroll
      for (int ni = 0; ni < 4; ni++) {
        int rowb = wn * 64 + ni * 16 + lrow;
        bv[ni] = *(const bf16x8*)((const char*)lds_b + rowb * 128 + sel * 16);
      }
#pragma unroll
      for (int mi = 0; mi < 4; mi++) {
        int rowa = wm * 64 + mi * 16 + lrow;
        bf16x8 av = *(const bf16x8*)((const char*)lds_a + rowa * 128 + sel * 16);
#pragma unroll
        for (int ni = 0; ni < 4; ni++)
          acc[mi][ni] =
              __builtin_amdgcn_mfma_f32_16x16x32_bf16(av, bv[ni], acc[mi][ni], 0, 0, 0);
      }
    }
    __syncthreads();
  }

  // ---- fused epilogue: exp, E store, ET store (LDS transpose), Z sums ----
  const int TS = 136;  // padded LDS row stride (u16) for 32x128 slice
  u16* T = lds_a;
  float colacc[4] = {0.f, 0.f, 0.f, 0.f};
#pragma unroll
  for (int s = 0; s < 4; s++) {
    if (wm == (s >> 1)) {
      int smi0 = (s & 1) * 2;
#pragma unroll
      for (int mi2 = 0; mi2 < 2; mi2++) {
        int mi = smi0 + mi2;
        float rowp[4] = {0.f, 0.f, 0.f, 0.f};
#pragma unroll
        for (int ni = 0; ni < 4; ni++) {
          int j = n0 + wn * 64 + ni * 16 + lrow;
          bool jv = j < 1600;
#pragma unroll
          for (int r = 0; r < 4; r++) {
            int i = m0 + wm * 64 + mi * 16 + lquad * 4 + r;
            float e = __expf(acc[mi][ni][r]);
            T[(mi2 * 16 + lquad * 4 + r) * TS + wn * 64 + ni * 16 + lrow] = f2bf(e);
            rowp[r] += jv ? e : 0.f;
            colacc[ni] += (i < 1600) ? e : 0.f;
          }
        }
#pragma unroll
        for (int r = 0; r < 4; r++) {
          float v = rowp[r];
          v += __shfl_xor(v, 1);
          v += __shfl_xor(v, 2);
          v += __shfl_xor(v, 4);
          v += __shfl_xor(v, 8);
          int i = m0 + wm * 64 + mi * 16 + lquad * 4 + r;
          if (lrow == 0 && i < 1600) atomicAdd(&Zrow[b * 1600 + i], v);
        }
      }
    }
    __syncthreads();
    // E rows: 32 rows x 128 cols, 16B coalesced stores
#pragma unroll
    for (int p = 0; p < 2; p++) {
      int jj = tid + p * 256;
      int ml = jj >> 4, n8 = jj & 15;
      int gi = m0 + s * 32 + ml, gj = n0 + n8 * 8;
      if (gi < 1600 && gj < 1600)
        *(uint4*)(Eb + (size_t)gi * 1600 + gj) = *(const uint4*)&T[ml * TS + n8 * 8];
    }
    // ET rows: transposed, 8B stores
#pragma unroll
    for (int p = 0; p < 4; p++) {
      int jj = tid + p * 256;
      int n = jj >> 3, m4 = jj & 7;
      int gm = m0 + s * 32 + m4 * 4, gn = n0 + n;
      if (gn < 1600 && gm < 1600) {
        ushort4 v;
        v.x = T[(m4 * 4 + 0) * TS + n];
        v.y = T[(m4 * 4 + 1) * TS + n];
        v.z = T[(m4 * 4 + 2) * TS + n];
        v.w = T[(m4 * 4 + 3) * TS + n];
        *(ushort4*)(ETb + (size_t)gn * 1600 + gm) = v;
      }
    }
    __syncthreads();
  }
#pragma unroll
  for (int ni = 0; ni < 4; ni++) {
    float v = colacc[ni];
    v += __shfl_xor(v, 16);
    v += __shfl_xor(v, 32);
    int j = n0 + wn * 64 + ni * 16 + lrow;
    if (lquad == 0 && j < 1600) atomicAdd(&Zcol[b * 1600 + j], v);
  }
}

// K3: out[idx] = bf16( x[idx] / Z[b][pixel] )   (both inputs via blockIdx.y)
__global__ void scale_div(const float* __restrict__ ex, const float* __restrict__ qu,
                          const float* __restrict__ Zcol, const float* __restrict__ Zrow,
                          u16* __restrict__ ebf, u16* __restrict__ qbf) {
  const float* x; const float* Z; u16* o;
  if (blockIdx.y == 0) { x = ex; Z = Zcol; o = ebf; }
  else { x = qu; Z = Zrow; o = qbf; }
  size_t idx = (size_t)blockIdx.x * 256 + threadIdx.x;  // 13,107,200
  int b = (int)(idx / 819200);
  int i = (int)(idx % 1600);
  o[idx] = f2bf(x[idx] / Z[b * 1600 + i]);
}

// ---------------------------------------------------------------------------
// K5: both 3x3 convs as A*B^T GEMM, BK=64, tap-structured K loop.
// W: [512][4608] (k=t*512+c), ATT: padded [b][42*42][512] bf16. out fp32.
// ---------------------------------------------------------------------------
__global__ __launch_bounds__(256) void conv_gemm64(
    const u16* __restrict__ W1, const u16* __restrict__ ATT1,
    const u16* __restrict__ W2, const u16* __restrict__ ATT2,
    float* __restrict__ out) {
  __shared__ u16 lds_a[128 * 64];
  __shared__ u16 lds_b[128 * 64];
  int tid = threadIdx.x;
  int z = blockIdx.z, b = z & 15, sel2 = z >> 4;
  const u16* W = sel2 ? W2 : W1;
  const u16* attb = (sel2 ? ATT2 : ATT1) + (size_t)b * 903168;
  float* outb = out + (size_t)b * 1638400 + (size_t)(sel2 ? 512 : 0) * 1600;
  int p0 = blockIdx.x * 128, o0 = blockIdx.y * 128;

  int rsub = tid >> 3;
  int gch = (tid & 7) ^ (rsub & 7);
  const char* pa[4];
  const char* pb[4];
#pragma unroll
  for (int c = 0; c < 4; c++) {
    int ro = o0 + 32 * c + rsub;  // < 512 always
    pa[c] = (const char*)(W + (size_t)ro * 4608) + gch * 16;
    int p = p0 + 32 * c + rsub; p = p < 1600 ? p : 1599;
    int y = p / 40, x = p - y * 40;
    pb[c] = (const char*)(attb + (size_t)(y * 42 + x) * 512) + gch * 16;
  }

  const f32x4 fzero = {0.f, 0.f, 0.f, 0.f};
  f32x4 acc[4][4];
#pragma unroll
  for (int mi = 0; mi < 4; mi++)
#pragma unroll
    for (int ni = 0; ni < 4; ni++) acc[mi][ni] = fzero;

  int wid = tid >> 6, lane = tid & 63;
  int wm = wid & 1, wn = wid >> 1;
  int lrow = lane & 15, lquad = lane >> 4;
  int sl = lrow & 7;

  int tapbyte = 0, dxc = 0;
  for (int t = 0; t < 9; t++) {
#pragma unroll 2
    for (int kc = 0; kc < 8; kc++) {
#pragma unroll
      for (int c = 0; c < 4; c++) {
        gll16(pa[c], (char*)lds_a + c * 4096 + tid * 16);
        gll16(pb[c] + tapbyte + kc * 128, (char*)lds_b + c * 4096 + tid * 16);
        pa[c] += 128;
      }
      __syncthreads();
#pragma unroll
      for (int k2 = 0; k2 < 2; k2++) {
        int sel = ((k2 << 2) | lquad) ^ sl;
        bf16x8 bv[4];
#pragma unroll
        for (int ni = 0; ni < 4; ni++) {
          int rowb = wn * 64 + ni * 16 + lrow;
          bv[ni] = *(const bf16x8*)((const char*)lds_b + rowb * 128 + sel * 16);
        }
#pragma unroll
        for (int mi = 0; mi < 4; mi++) {
          int rowa = wm * 64 + mi * 16 + lrow;
          bf16x8 av = *(const bf16x8*)((const char*)lds_a + rowa * 128 + sel * 16);
#pragma unroll
          for (int ni = 0; ni < 4; ni++)
            acc[mi][ni] = __builtin_amdgcn_mfma_f32_16x16x32_bf16(av, bv[ni],
                                                                  acc[mi][ni], 0, 0, 0);
        }
      }
      __syncthreads();
    }
    dxc++;
    tapbyte += 1024;
    if (dxc == 3) { dxc = 0; tapbyte += 39 * 1024; }
  }

#pragma unroll
  for (int mi = 0; mi < 4; mi++) {
#pragma unroll
    for (int r = 0; r < 4; r++) {
      int o = o0 + wm * 64 + mi * 16 + lquad * 4 + r;
#pragma unroll
      for (int ni = 0; ni < 4; ni++) {
        int p = p0 + wn * 64 + ni * 16 + lrow;
        if (p < 1600) outb[(size_t)o * 1600 + p] = acc[mi][ni][r];
      }
    }
  }
}

// ---------------------------------------------------------------------------
extern "C" void kernel_launch(void* const* d_in, const int* in_sizes, int n_in,
                              void* d_out, int out_size, void* d_ws, size_t ws_size,
                              hipStream_t stream) {
  const float* ex = (const float*)d_in[0];
  const float* qu = (const float*)d_in[1];
  const float* w_e = (const float*)d_in[2];
  const float* w_q = (const float*)d_in[3];
  const float* w_c1 = (const float*)d_in[4];
  const float* w_c2 = (const float*)d_in[5];
  float* out = (float*)d_out;
  char* ws = (char*)d_ws;

  u16* E     = (u16*)(ws + 0L);            // 81,920,000
  u16* ET    = (u16*)(ws + 81920000L);     // 81,920,000
  u16* xt_e  = (u16*)(ws + 163840000L);    // 26,214,400 (reused as ebf)
  u16* xt_q  = (u16*)(ws + 190054400L);    // 26,214,400 (reused as qbf)
  u16* ecorr = (u16*)(ws + 216268800L);    // 13,107,200
  u16* qcorr = (u16*)(ws + 229376000L);    // 13,107,200
  u16* att_e = (u16*)(ws + 242483200L);    // 28,901,376
  u16* att_q = (u16*)(ws + 271384576L);    // 28,901,376
  float* Zrow = (float*)(ws + 300285952L); // 102,400
  float* Zcol = (float*)(ws + 300388352L); // 102,400
  u16* w_ebf = (u16*)(ws + 300490752L);    // 262,144
  u16* w_qbf = (u16*)(ws + 300752896L);    // 262,144
  u16* wr1   = (u16*)(ws + 301015040L);    // 4,718,592
  u16* wr2   = (u16*)(ws + 305733632L);    // 4,718,592  (total 310,452,224)

  // prep
  transp_cast_x2<<<dim3(50, 16, 32), 256, 0, stream>>>(ex, qu, xt_e, xt_q);
  cast_w<<<dim3(512), 256, 0, stream>>>(w_e, w_q, w_ebf, w_qbf);
  repack_wc<<<dim3(9216, 2), 256, 0, stream>>>(w_c1, w_c2, wr1, wr2);
  // zero att_e, att_q, Zrow, Zcol (contiguous): 58,007,552 B
  zero_mem<<<dim3(2048), 256, 0, stream>>>((uint4*)att_e, 3625472L);

  // K1: corr[b][n][o] = sum_c xt[n,c] * w[o,c]   (both e and q in one grid)
  gemm_bt64<0><<<dim3(13, 2, 32), 256, 0, stream>>>(
      xt_e, w_ebf, ecorr, xt_q, w_qbf, qcorr, 1600, 256, 512, 819200L, 0L, 409600L);

  // K2: E/ET/Zrow/Zcol fused
  gemm_corr_exp<<<dim3(13, 13, 16), 256, 0, stream>>>(ecorr, qcorr, E, ET, Zrow, Zcol);

  // K3: scale inputs by softmax denominators
  u16* ebf = xt_e;
  u16* qbf = xt_q;
  scale_div<<<dim3(51200, 2), 256, 0, stream>>>(ex, qu, Zcol, Zrow, ebf, qbf);

  // K4: att_q[p][c] = sum_i E[p,i]*ebf[c,i] ; att_e[p][c] = sum_i ET[p,i]*qbf[c,i]
  gemm_bt64<2><<<dim3(13, 4, 32), 256, 0, stream>>>(
      E, ebf, att_q, ET, qbf, att_e, 1600, 512, 1600, 2560000L, 819200L, 903168L);

  // K5: both convs; ch 0..511 = conv(att_e, w_c1), 512..1023 = conv(att_q, w_c2)
  conv_gemm64<<<dim3(13, 4, 32), 256, 0, stream>>>(wr1, att_e, wr2, att_q, out);
}